// Round 9
// baseline (20033.676 us; speedup 1.0000x reference)
//
#include <hip/hip_runtime.h>
#include <stdint.h>

typedef _Float16 h2 __attribute__((ext_vector_type(2)));
typedef float    f4 __attribute__((ext_vector_type(4)));
typedef uint32_t u4 __attribute__((ext_vector_type(4)));

__device__ __forceinline__ float dot2(uint32_t a, uint32_t b, float c) {
    return __builtin_amdgcn_fdot2(__builtin_bit_cast(h2, a),
                                  __builtin_bit_cast(h2, b), c, false);
}

// tanh(z) = 1 - 2/(exp(2z)+1)
__device__ __forceinline__ float fast_tanh(float z) {
    float e = __expf(2.0f * z);
    return 1.0f - 2.0f * __builtin_amdgcn_rcpf(e + 1.0f);
}

#define TT 4096
#define NBAT 32
#define HD 512
#define HALF 256
#define FSTRIDE 4100                       // flag slots per block (>= TT+1)
#define FLAGS_BYTES (64 * FSTRIDE * 4)
#define PUB_OFF 1114112                    // 1 MB + 64 KB, past flags
#define WS_NEED (PUB_OFF + (size_t)64 * 2 * HALF * 2)

// 8 dot2 per state-quad q (2 cols). q compile-time -> static wr indices.
#define DOTQ(sq, q)                                                          \
    if ((q) & 1) {                                                           \
        d0b = dot2((sq)[0], wr0[4*(q)+0], d0b);                              \
        d0b = dot2((sq)[1], wr0[4*(q)+1], d0b);                              \
        d0b = dot2((sq)[2], wr0[4*(q)+2], d0b);                              \
        d0b = dot2((sq)[3], wr0[4*(q)+3], d0b);                              \
        d1b = dot2((sq)[0], wr1[4*(q)+0], d1b);                              \
        d1b = dot2((sq)[1], wr1[4*(q)+1], d1b);                              \
        d1b = dot2((sq)[2], wr1[4*(q)+2], d1b);                              \
        d1b = dot2((sq)[3], wr1[4*(q)+3], d1b);                              \
    } else {                                                                 \
        d0a = dot2((sq)[0], wr0[4*(q)+0], d0a);                              \
        d0a = dot2((sq)[1], wr0[4*(q)+1], d0a);                              \
        d0a = dot2((sq)[2], wr0[4*(q)+2], d0a);                              \
        d0a = dot2((sq)[3], wr0[4*(q)+3], d0a);                              \
        d1a = dot2((sq)[0], wr1[4*(q)+0], d1a);                              \
        d1a = dot2((sq)[1], wr1[4*(q)+1], d1a);                              \
        d1a = dot2((sq)[2], wr1[4*(q)+2], d1a);                              \
        d1a = dot2((sq)[3], wr1[4*(q)+3], d1a);                              \
    }

// PAIR KERNEL: 64 blocks x 512 threads. Block = (row, side): owns 256 cols of
// one batch row, contracts the FULL K=512. Per-thread W = 2 cols x 64 k-pairs
// = 128 reg words -> entirely register-resident (rounds 2-8 proved AGPR
// sourcing of dot2 is free and that >208 live words spills). VALU floor
// halves: 128 dot2/thread -> 1024 cyc/SIMD.
//
// Cross-block state exchange per step (512 B): publish own half as fp16 +
// release-flag (agent scope); partner spin-acquires then broadcast-reads.
// Pairing bid^8 -> same XCD under round-robin dispatch (perf-only heuristic).
// Flag gating bounds skew to <=1 step -> 2-slot ping-pong pub is race-free.
// Flags are zeroed by hipMemsetAsync each call (replay/poison-safe).
// Waves 0-3 (kh 0,1) use the LOCAL half (no wait); waves 4-7 (kh 2,3) absorb
// the flag/pub latency while co-scheduled waves crunch -> latency hidden.
// asm "+v" on the pub pointer defeats uniformity -> vector (not scalar-cache)
// loads, made fresh by the acquire.
__global__ __launch_bounds__(512, 1)
void esn_pair(const float* __restrict__ X, const float* __restrict__ W_in,
              const float* __restrict__ W_int, const float* __restrict__ noise,
              float* __restrict__ out, int* flags, _Float16* pub)
{
    __shared__ __align__(16) _Float16 s_buf[2][HALF];  // my half, fp16, dbuf
    __shared__ float pads[4][HALF];                    // 4-way k partials

    const int tid  = threadIdx.x;
    const int bid  = blockIdx.x;
    const int row  = (bid >> 4) * 8 + (bid & 7);   // pair (b, b^8): same XCD
    const int side = (bid >> 3) & 1;
    const int hb   = side * HALF;                  // my column half base
    const int pr   = bid ^ 8;                      // partner block
    const int kh   = tid >> 7;                     // k-slice 0..3 (128 wide)
    const int colg = tid & 127;
    const int c0   = hb + colg * 2;                // my 2 output columns

    // k-slices: kh 0,1 -> MY half of state (local); kh 2,3 -> partner half.
    const int ksb = ((kh < 2) ? hb : (hb ^ HALF)) + (kh & 1) * 128;

    // ---- Prologue: pack this thread's W (2 cols x 64 pairs, fp16) ----
    uint32_t wr0[64], wr1[64];                     // 128 words, all static idx
    #pragma unroll
    for (int p = 0; p < 64; ++p) {
        const int k = ksb + 2 * p;
        h2 a, b;
        a[0] = (_Float16)W_int[(size_t)k * HD + c0];
        a[1] = (_Float16)W_int[(size_t)(k + 1) * HD + c0];
        b[0] = (_Float16)W_int[(size_t)k * HD + c0 + 1];
        b[1] = (_Float16)W_int[(size_t)(k + 1) * HD + c0 + 1];
        wr0[p] = __builtin_bit_cast(uint32_t, a);
        wr1[p] = __builtin_bit_cast(uint32_t, b);
    }
    float win0 = 0.f, win1 = 0.f, win2 = 0.f;
    if (tid < HALF) {
        const int mc = hb + tid;
        win0 = W_in[mc*3 + 0]; win1 = W_in[mc*3 + 1]; win2 = W_in[mc*3 + 2];
        s_buf[0][tid] = (_Float16)0.01f;
    }
    __syncthreads();

    const float* Xb     = X   + (size_t)row * TT * 3;
    float*       outb   = out + (size_t)row * TT * HD;
    int*         myflag = flags + bid * FSTRIDE;
    const int*   prflag = flags + pr  * FSTRIDE;
    _Float16*       mypub = pub + (size_t)bid * 2 * HALF;
    const _Float16* prpub = pub + (size_t)pr  * 2 * HALF;

    int cur = 0;
    for (int t = 0; t < TT; ++t) {
        // epilogue operands, loaded early (latency hides under dot phase)
        float nz = 0.f, x0 = 0.f, x1 = 0.f, x2 = 0.f;
        if (tid < HALF) {
            nz = noise[((size_t)t * NBAT + row) * HD + hb + tid];
            x0 = Xb[t*3 + 0]; x1 = Xb[t*3 + 1]; x2 = Xb[t*3 + 2];
        }

        float d0a = 0.f, d0b = 0.f, d1a = 0.f, d1b = 0.f;
        if (kh < 2) {
            // local half: LDS broadcast quads
            const u4* sb4 = ((const u4*)&s_buf[cur][0]) + (kh & 1) * 16;
            #pragma unroll
            for (int q = 0; q < 16; ++q) { const u4 sq = sb4[q]; DOTQ(sq, q); }
        } else if (t > 0) {
            // partner half: spin-acquire flag, then vector broadcast loads
            const int* fp = prflag + t;
            int guard = 0;
            while (__hip_atomic_load(fp, __ATOMIC_ACQUIRE,
                                     __HIP_MEMORY_SCOPE_AGENT) == 0) {
                __builtin_amdgcn_s_sleep(1);
                if (++guard > 65536) break;      // safety valve (no hang)
            }
            const u4* pb4 = ((const u4*)(prpub + (size_t)(t & 1) * HALF))
                            + (kh & 1) * 16;
            asm volatile("" : "+v"(pb4));        // defeat uniformity -> VMEM
            #pragma unroll
            for (int q = 0; q < 16; ++q) { const u4 sq = pb4[q]; DOTQ(sq, q); }
        } else {
            // t == 0: partner state is the known constant 0.01
            h2 cc; cc[0] = (_Float16)0.01f; cc[1] = (_Float16)0.01f;
            const uint32_t c01 = __builtin_bit_cast(uint32_t, cc);
            u4 sq; sq[0] = c01; sq[1] = c01; sq[2] = c01; sq[3] = c01;
            #pragma unroll
            for (int q = 0; q < 16; ++q) { DOTQ(sq, q); }
        }
        *(float2*)&pads[kh][colg * 2] = make_float2(d0a + d0b, d1a + d1b);
        __syncthreads();

        // ---- epilogue: reduce 4 k-slices, tanh, emit + publish ----
        if (tid < HALF) {
            float z = pads[0][tid] + pads[1][tid] + pads[2][tid] + pads[3][tid]
                    + win0*x0 + win1*x1 + win2*x2 + 0.01f*nz;
            const float s = fast_tanh(z);
            outb[(size_t)t * HD + hb + tid] = s;
            s_buf[cur ^ 1][tid] = (_Float16)s;
            mypub[(size_t)((t + 1) & 1) * HALF + tid] = (_Float16)s;
        }
        __syncthreads();     // drains all stores (vmcnt 0) before flag
        if (tid == 0)
            __hip_atomic_store(myflag + (t + 1), 1, __ATOMIC_RELEASE,
                               __HIP_MEMORY_SCOPE_AGENT);
        cur ^= 1;
    }
}

// ---------- Fallback: proven single-CU kernel (round 5, 5376 us) ----------
#define JL 12
#define JTOT 64
#define JR (JTOT - JL)

__global__ __launch_bounds__(512, 1)
void esn_single(const float* __restrict__ X, const float* __restrict__ W_in,
                const float* __restrict__ W_int, const float* __restrict__ noise,
                float* __restrict__ out)
{
    __shared__ __align__(16) _Float16 s_buf[2][HD];
    __shared__ float pads[4][HD];
    __shared__ u4 wstash[8 * JL * 64];

    const int tid  = threadIdx.x;
    const int b    = blockIdx.x;
    const int w    = tid >> 6;
    const int l    = tid & 63;
    const int kg   = tid >> 7;
    const int colg = tid & 127;
    const int c0   = colg * 4;

    const float win0 = W_in[tid*3 + 0];
    const float win1 = W_in[tid*3 + 1];
    const float win2 = W_in[tid*3 + 2];

    uint32_t wreg[4][JR];
    {
        const f4* Wv = (const f4*)W_int;
        for (int j = 0; j < JL; ++j) {
            const int k = kg*128 + 2*j;
            f4 r0 = Wv[(size_t)k*128 + colg];
            f4 r1 = Wv[(size_t)(k+1)*128 + colg];
            u4 q;
            #pragma unroll
            for (int c = 0; c < 4; ++c) {
                h2 hw; hw[0] = (_Float16)r0[c]; hw[1] = (_Float16)r1[c];
                q[c] = __builtin_bit_cast(uint32_t, hw);
            }
            wstash[(w*JL + j)*64 + l] = q;
        }
        #pragma unroll
        for (int j = 0; j < JR; ++j) {
            const int k = kg*128 + 2*(JL + j);
            f4 r0 = Wv[(size_t)k*128 + colg];
            f4 r1 = Wv[(size_t)(k+1)*128 + colg];
            #pragma unroll
            for (int c = 0; c < 4; ++c) {
                h2 hw; hw[0] = (_Float16)r0[c]; hw[1] = (_Float16)r1[c];
                wreg[c][j] = __builtin_bit_cast(uint32_t, hw);
            }
        }
    }
    s_buf[0][tid] = (_Float16)0.01f;
    __syncthreads();

    const float* Xb   = X   + (size_t)b * TT * 3;
    float*       outb = out + (size_t)b * TT * HD;
    const size_t nb   = (size_t)b * HD + tid;

    int cur = 0;
    for (int t = 0; t < TT; ++t) {
        const float nz = noise[(size_t)t*(NBAT*HD) + nb];
        const float x0 = Xb[t*3 + 0];
        const float x1 = Xb[t*3 + 1];
        const float x2 = Xb[t*3 + 2];

        const u4* sv4 = (const u4*)((const uint32_t*)(&s_buf[cur][0]) + kg*64);
        float a0 = 0.f, a1 = 0.f, a2 = 0.f, a3 = 0.f;
        u4 sq;

        #pragma unroll
        for (int j = 0; j < JL; ++j) {
            if ((j & 3) == 0) sq = sv4[j >> 2];
            const uint32_t sv = sq[j & 3];
            u4 q = wstash[(w*JL + j)*64 + l];
            a0 = dot2(sv, q[0], a0);
            a1 = dot2(sv, q[1], a1);
            a2 = dot2(sv, q[2], a2);
            a3 = dot2(sv, q[3], a3);
        }
        #pragma unroll
        for (int j = 0; j < JR; ++j) {
            const int jg = JL + j;
            if ((jg & 3) == 0) sq = sv4[jg >> 2];
            const uint32_t sv = sq[jg & 3];
            a0 = dot2(sv, wreg[0][j], a0);
            a1 = dot2(sv, wreg[1][j], a1);
            a2 = dot2(sv, wreg[2][j], a2);
            a3 = dot2(sv, wreg[3][j], a3);
        }
        f4 pv; pv[0] = a0; pv[1] = a1; pv[2] = a2; pv[3] = a3;
        *(f4*)&pads[kg][c0] = pv;
        __syncthreads();

        float z = pads[0][tid] + pads[1][tid] + pads[2][tid] + pads[3][tid];
        z += win0*x0 + win1*x1 + win2*x2 + 0.01f*nz;
        const float s = fast_tanh(z);
        outb[(size_t)t*HD + tid] = s;
        s_buf[cur^1][tid] = (_Float16)s;
        __syncthreads();
        cur ^= 1;
    }
}

extern "C" void kernel_launch(void* const* d_in, const int* in_sizes, int n_in,
                              void* d_out, int out_size, void* d_ws, size_t ws_size,
                              hipStream_t stream)
{
    const float* X     = (const float*)d_in[0];
    const float* W_in  = (const float*)d_in[1];
    const float* W_int = (const float*)d_in[2];
    const float* noise = (const float*)d_in[3];
    float* out = (float*)d_out;

    if (ws_size >= WS_NEED) {
        hipMemsetAsync(d_ws, 0, FLAGS_BYTES, stream);   // graph-capture-safe
        esn_pair<<<dim3(64), dim3(512), 0, stream>>>(
            X, W_in, W_int, noise, out,
            (int*)d_ws, (_Float16*)((char*)d_ws + PUB_OFF));
    } else {
        esn_single<<<dim3(32), dim3(512), 0, stream>>>(X, W_in, W_int, noise, out);
    }
}

// Round 10
// 5696.310 us; speedup vs baseline: 3.5170x; 3.5170x over previous
//
#include <hip/hip_runtime.h>
#include <stdint.h>

typedef _Float16 h2 __attribute__((ext_vector_type(2)));
typedef float    f4 __attribute__((ext_vector_type(4)));
typedef uint32_t u4 __attribute__((ext_vector_type(4)));

__device__ __forceinline__ float dot2(uint32_t a, uint32_t b, float c) {
    return __builtin_amdgcn_fdot2(__builtin_bit_cast(h2, a),
                                  __builtin_bit_cast(h2, b), c, false);
}

// tanh(z) = 1 - 2/(exp(2z)+1)
__device__ __forceinline__ float fast_tanh(float z) {
    float e = __expf(2.0f * z);
    return 1.0f - 2.0f * __builtin_amdgcn_rcpf(e + 1.0f);
}

#define TT 4096
#define NB 32
#define HD 512
#define NLQ 12             // LDS-resident W quads per thread, at j = 5*i (i<12)
#define NRJ 52             // register-resident k-pairs per col (64 - 12)

// Round-2/5 structure (best verified: 5375 us) + ILP fixes only.
// 512 threads: kg = tid>>7 (128-row k-slice), colg = tid&127 (4 cols).
// W_int as fp16 half2 k-pairs: 52/col in registers, 12/col in LDS.
//
// ILP changes vs round 5 (attacking the ~900 cyc/step VALU-idle stall):
//  - LDS W quads re-mapped to j = 5i (interleaved with reg pairs), prefetched
//    2-deep: ds_read issued 10 j's (~160 dot2 cyc) before use, covered by
//    reg-part dot2s. Round 5 consumed them 0-deep (~120 cyc raw latency).
//  - State quads in a 3-slot rotation refilled 2 groups (~128 cyc) ahead.
//  - Deferred out-store: step t-1's value stored at step t top, so the
//    vmcnt drain at barrier 1 lands after ~2000 cyc of dot work.
//  - W_in moved to LDS (-3 regs).
// All slot/array indices unroll-constant (no scratch). Register budget:
// wreg 208 + wl 8 + sqs 12 + working ~17 = ~245 < 256 (round 6/8 spilled
// at ~+40 over; this is +14 over the proven round-5 allocation).
__global__ __launch_bounds__(512, 1)
void esn_kernel(const float* __restrict__ X, const float* __restrict__ W_in,
                const float* __restrict__ W_int, const float* __restrict__ noise,
                float* __restrict__ out)
{
    __shared__ __align__(16) _Float16 s_buf[2][HD];  // 2 KB state (fp16, dbuf)
    __shared__ float pads[4][HD];                    // 8 KB per-kg partials
    __shared__ u4 wstash[8 * NLQ * 64];              // 96 KB LDS W quads
    __shared__ float win_lds[HD][3];                 // 6 KB input weights

    const int tid  = threadIdx.x;
    const int b    = blockIdx.x;
    const int w    = tid >> 6;      // wave 0..7
    const int l    = tid & 63;      // lane 0..63
    const int kg   = tid >> 7;      // 0..3 (k-slice of 128 state rows)
    const int colg = tid & 127;     // 0..127
    const int c0   = colg * 4;      // first of this thread's 4 columns

    win_lds[tid][0] = W_in[tid*3 + 0];
    win_lds[tid][1] = W_in[tid*3 + 1];
    win_lds[tid][2] = W_in[tid*3 + 2];

    // ---- Prologue: pack W_int (fp32 [k][h] -> fp16 half2 k-pairs) ----
    // k-pair j (k = kg*128 + 2j): j = 5i (i<12) -> LDS quad i; else register
    // slot ri = j - (j<56 ? j/5+1 : 12). Unrolled -> all indices static.
    uint32_t wreg[4][NRJ];
    {
        const f4* Wv = (const f4*)W_int;
        #pragma unroll
        for (int j = 0; j < 64; ++j) {
            const int k = kg*128 + 2*j;
            f4 r0 = Wv[(size_t)k*128 + colg];
            f4 r1 = Wv[(size_t)(k+1)*128 + colg];
            u4 q;
            #pragma unroll
            for (int c = 0; c < 4; ++c) {
                h2 hw; hw[0] = (_Float16)r0[c]; hw[1] = (_Float16)r1[c];
                q[c] = __builtin_bit_cast(uint32_t, hw);
            }
            if (j % 5 == 0 && j < 56) {
                wstash[(w*NLQ + j/5)*64 + l] = q;
            } else {
                const int ri = j - (j < 56 ? j/5 + 1 : 12);
                wreg[0][ri] = q[0]; wreg[1][ri] = q[1];
                wreg[2][ri] = q[2]; wreg[3][ri] = q[3];
            }
        }
    }
    s_buf[0][tid] = (_Float16)0.01f;   // prev0 = 0.01
    __syncthreads();

    const float* Xb   = X   + (size_t)b * TT * 3;
    float*       outb = out + (size_t)b * TT * HD;
    const size_t nb   = (size_t)b * HD + tid;
    const u4*    wv   = &wstash[(w*NLQ)*64 + l];   // LDS quad i at wv[i*64]

    float o_prev = 0.f;
    int cur = 0;
    for (int t = 0; t < TT; ++t) {
        // Deferred store: step t-1's output, drains under this step's dots.
        if (t > 0) outb[(size_t)(t-1)*HD + tid] = o_prev;
        const float nz = noise[(size_t)t*(NB*HD) + nb];
        const float x0 = Xb[t*3 + 0];
        const float x1 = Xb[t*3 + 1];
        const float x2 = Xb[t*3 + 2];

        // ---- Phase A: 256 dot2 over this thread's k-slice ----
        const u4* sv4 = (const u4*)((const uint32_t*)(&s_buf[cur][0]) + kg*64);
        u4 sqs[3] = {sv4[0], sv4[1], sv4[2]};   // 3-slot state rotation
        u4 wl[2]  = {wv[0], wv[64]};            // 2-deep W-quad prefetch
        float a0 = 0.f, a1 = 0.f, a2 = 0.f, a3 = 0.f;

        #pragma unroll
        for (int j = 0; j < 64; ++j) {
            const int g = j >> 2;               // state quad group 0..15
            if ((j & 3) == 0 && g >= 1 && g <= 13)
                sqs[(g - 1) % 3] = sv4[g + 2];  // refill 2 groups ahead
            const uint32_t sv = sqs[g % 3][j & 3];
            if (j % 5 == 0 && j < 56) {         // LDS-resident W pair
                const int i = j / 5;
                const u4 q = wl[i & 1];
                a0 = dot2(sv, q[0], a0);
                a1 = dot2(sv, q[1], a1);
                a2 = dot2(sv, q[2], a2);
                a3 = dot2(sv, q[3], a3);
                if (i + 2 < NLQ) wl[i & 1] = wv[(i + 2) * 64];
            } else {                            // register-resident W pair
                const int ri = j - (j < 56 ? j/5 + 1 : 12);
                a0 = dot2(sv, wreg[0][ri], a0);
                a1 = dot2(sv, wreg[1][ri], a1);
                a2 = dot2(sv, wreg[2][ri], a2);
                a3 = dot2(sv, wreg[3][ri], a3);
            }
        }
        f4 pv; pv[0] = a0; pv[1] = a1; pv[2] = a2; pv[3] = a3;
        *(f4*)&pads[kg][c0] = pv;
        __syncthreads();

        // ---- Phase B: reduce 4 k-slices, add input+noise, tanh ----
        float z = pads[0][tid] + pads[1][tid] + pads[2][tid] + pads[3][tid];
        z += win_lds[tid][0]*x0 + win_lds[tid][1]*x1 + win_lds[tid][2]*x2
           + 0.01f*nz;
        const float s = fast_tanh(z);
        o_prev = s;                          // stored at next step's top
        s_buf[cur^1][tid] = (_Float16)s;
        __syncthreads();
        cur ^= 1;
    }
    outb[(size_t)(TT-1)*HD + tid] = o_prev;  // flush final step
}

extern "C" void kernel_launch(void* const* d_in, const int* in_sizes, int n_in,
                              void* d_out, int out_size, void* d_ws, size_t ws_size,
                              hipStream_t stream)
{
    const float* X     = (const float*)d_in[0];
    const float* W_in  = (const float*)d_in[1];
    const float* W_int = (const float*)d_in[2];
    const float* noise = (const float*)d_in[3];
    float* out = (float*)d_out;

    esn_kernel<<<dim3(NB), dim3(512), 0, stream>>>(X, W_in, W_int, noise, out);
}